// Round 14
// baseline (582.284 us; speedup 1.0000x reference)
//
#include <hip/hip_runtime.h>
#include <cstdint>
#include <cstddef>

typedef __bf16 bf16_t;
typedef __bf16 bf16x8 __attribute__((ext_vector_type(8)));
typedef float f32x4 __attribute__((ext_vector_type(4)));

// Problem dims
#define BB 4
#define SS 1024
#define HH 2048
#define NHH 32
#define HDD 64
#define MTOK 4096   // B*S
#define QKVLD 6144  // fused qkv row stride (elements)

// -------- workspace layout (bytes), total 251,658,240 (240 MiB) --------
static constexpr size_t OFF_WQKV   = 0;
static constexpr size_t OFF_WDENSE = 25165824;
static constexpr size_t OFF_WH4H   = 33554432;
static constexpr size_t OFF_W4HH   = 67108864;
static constexpr size_t OFF_X1     = 100663296;
static constexpr size_t OFF_QKV    = 117440512;
static constexpr size_t OFF_ATTND2 = 150994944;
static constexpr size_t OFF_VT     = 167772160;
static constexpr size_t OFF_LNIN   = 184549376;   // bf16 8 MB
static constexpr size_t OFF_MLP    = 218103808;
static constexpr size_t OFF_MLP2   = 234881024;

__device__ __forceinline__ uint16_t f2bfu(float f) {
  union { float f; uint32_t u; } v; v.f = f;
  return (uint16_t)((v.u + 0x7FFFu + ((v.u >> 16) & 1u)) >> 16);
}
__device__ __forceinline__ bf16_t f2bf(float f) {
  union { uint16_t u; bf16_t b; } o; o.u = f2bfu(f);
  return o.b;
}
__device__ __forceinline__ float bfu2f(uint16_t u) {
  union { uint32_t u; float f; } v; v.u = ((uint32_t)u) << 16;
  return v.f;
}

__device__ __forceinline__ void g2l16(const void* g, void* l) {
  __builtin_amdgcn_global_load_lds(
      (const __attribute__((address_space(1))) void*)g,
      (__attribute__((address_space(3))) void*)l, 16, 0, 0);
}

// ---------------- row helpers (rows of 2048, 256 flat threads, 8 elems/thread) ----------------
// Element layout: thread tid owns cols {4*tid..4*tid+3} and {1024+4*tid..+3}.
__device__ __forceinline__ void block_reduce2(int tid, float& s, float& ss) {
#pragma unroll
  for (int o = 32; o > 0; o >>= 1) {
    s += __shfl_down(s, o, 64);
    ss += __shfl_down(ss, o, 64);
  }
  __shared__ float red[8];
  const int wave = tid >> 6;
  const int lane = tid & 63;
  if (lane == 0) { red[wave] = s; red[4 + wave] = ss; }
  __syncthreads();
  s = red[0] + red[1] + red[2] + red[3];
  ss = red[4] + red[5] + red[6] + red[7];
  __syncthreads();
}

__device__ __forceinline__ void load8(const float* base, int tid, float* v) {
  float4 a = ((const float4*)base)[tid];
  float4 b = ((const float4*)base)[tid + 256];
  v[0] = a.x; v[1] = a.y; v[2] = a.z; v[3] = a.w;
  v[4] = b.x; v[5] = b.y; v[6] = b.z; v[7] = b.w;
}
__device__ __forceinline__ void load8bf(const bf16_t* base, int tid, float* v) {
  ushort4 a = ((const ushort4*)base)[tid];
  ushort4 b = ((const ushort4*)base)[tid + 256];
  v[0] = bfu2f(a.x); v[1] = bfu2f(a.y); v[2] = bfu2f(a.z); v[3] = bfu2f(a.w);
  v[4] = bfu2f(b.x); v[5] = bfu2f(b.y); v[6] = bfu2f(b.z); v[7] = bfu2f(b.w);
}
__device__ __forceinline__ void store8f(float* base, int tid, const float* v) {
  ((float4*)base)[tid] = make_float4(v[0], v[1], v[2], v[3]);
  ((float4*)base)[tid + 256] = make_float4(v[4], v[5], v[6], v[7]);
}
__device__ __forceinline__ void store8bf(bf16_t* base, int tid, const float* v) {
  ushort4 o0 = {f2bfu(v[0]), f2bfu(v[1]), f2bfu(v[2]), f2bfu(v[3])};
  ushort4 o1 = {f2bfu(v[4]), f2bfu(v[5]), f2bfu(v[6]), f2bfu(v[7])};
  ((ushort4*)base)[tid] = o0;
  ((ushort4*)base)[tid + 256] = o1;
}
__device__ __forceinline__ void row_stats(int tid, const float* v, float& mean, float& inv) {
  float s = 0.f, ss = 0.f;
#pragma unroll
  for (int i = 0; i < 8; ++i) { s += v[i]; ss += v[i] * v[i]; }
  block_reduce2(tid, s, ss);
  mean = s * (1.0f / 2048.0f);
  float var = ss * (1.0f / 2048.0f) - mean * mean;
  inv = rsqrtf(var + 1e-5f);
}

// ---------------- merged: weight convert+transpose (4 weights) + LN1, 1 launch ----------------
__global__ void convert_ln1_kernel(const float* __restrict__ w0, bf16_t* __restrict__ o0,
                                   const float* __restrict__ w1, bf16_t* __restrict__ o1,
                                   const float* __restrict__ w2, bf16_t* __restrict__ o2,
                                   const float* __restrict__ w3, bf16_t* __restrict__ o3,
                                   const float* __restrict__ hid,
                                   const float* __restrict__ ln1w, const float* __restrict__ ln1b,
                                   bf16_t* __restrict__ x1) {
  const int id = blockIdx.x;
  const int tx = threadIdx.x & 31, ty = threadIdx.x >> 5;
  if (id >= 49152) {   // LN1 rows
    const int row = id - 49152, tid = threadIdx.x;
    float v[8], wv[8], bv[8], o[8];
    load8(hid + (size_t)row * HH, tid, v);
    float mean, inv;
    row_stats(tid, v, mean, inv);
    load8(ln1w, tid, wv);
    load8(ln1b, tid, bv);
#pragma unroll
    for (int i = 0; i < 8; ++i) o[i] = (v[i] - mean) * inv * wv[i] + bv[i];
    store8bf(x1 + (size_t)row * HH, tid, o);
    return;
  }
  __shared__ float t[32][33];
  const float* W; bf16_t* WT; int K, N, nt, idx;
  if (id < 12288)      { W = w0; WT = o0; K = 2048; N = 6144; nt = 192; idx = id; }
  else if (id < 16384) { W = w1; WT = o1; K = 2048; N = 2048; nt = 64;  idx = id - 12288; }
  else if (id < 32768) { W = w2; WT = o2; K = 2048; N = 8192; nt = 256; idx = id - 16384; }
  else                 { W = w3; WT = o3; K = 8192; N = 2048; nt = 64;  idx = id - 32768; }
  const int n0 = (idx % nt) * 32;
  const int k0 = (idx / nt) * 32;
#pragma unroll
  for (int j = 0; j < 4; ++j)
    t[ty + j * 8][tx] = W[(size_t)(k0 + ty + j * 8) * N + n0 + tx];
  __syncthreads();
#pragma unroll
  for (int j = 0; j < 4; ++j)
    WT[(size_t)(n0 + ty + j * 8) * K + k0 + tx] = f2bf(t[tx][ty + j * 8]);
}

// ---------------- v (strided in fused qkv) -> vT [B,NH,HD,S] (bf16) ----------------
__global__ void transpose_v_kernel(const bf16_t* __restrict__ qkv, bf16_t* __restrict__ vT) {
  __shared__ bf16_t t[32][33];
  const int s0 = blockIdx.x * 32;
  const int d0 = blockIdx.y * 32;
  const int bh = blockIdx.z;
  const int b = bh >> 5, h = bh & 31;
  const int tx = threadIdx.x, ty = threadIdx.y;
  const bf16_t* src = qkv + (size_t)b * SS * QKVLD + 2 * HH + h * HDD;
#pragma unroll
  for (int j = 0; j < 4; ++j)
    t[ty + j * 8][tx] = src[(size_t)(s0 + ty + j * 8) * QKVLD + d0 + tx];
  __syncthreads();
  bf16_t* dst = vT + (size_t)bh * HDD * SS;
#pragma unroll
  for (int j = 0; j < 4; ++j)
    dst[(size_t)(d0 + ty + j * 8) * SS + s0 + tx] = t[tx][ty + j * 8];
}

// LN3(ad+ad2) ; lnin = hidden + ln3 (bf16) ; x2 = LN2(lnin) bf16
__global__ __launch_bounds__(256) void fuse_mid_kernel(
    const bf16_t* __restrict__ ad, const bf16_t* __restrict__ ad2,
    const float* __restrict__ hid,
    const float* __restrict__ w3, const float* __restrict__ b3,
    const float* __restrict__ w2, const float* __restrict__ b2,
    bf16_t* __restrict__ lnin, bf16_t* __restrict__ x2) {
  const int row = blockIdx.x, tid = threadIdx.x;
  float a[8], a2[8], h[8], wv[8], bv[8], l[8], o[8];
  load8bf(ad + (size_t)row * HH, tid, a);
  load8bf(ad2 + (size_t)row * HH, tid, a2);
#pragma unroll
  for (int i = 0; i < 8; ++i) a[i] += a2[i];
  float mean3, inv3;
  row_stats(tid, a, mean3, inv3);
  load8(hid + (size_t)row * HH, tid, h);
  load8(w3, tid, wv);
  load8(b3, tid, bv);
#pragma unroll
  for (int i = 0; i < 8; ++i) l[i] = h[i] + (a[i] - mean3) * inv3 * wv[i] + bv[i];
  store8bf(lnin + (size_t)row * HH, tid, l);
  float mean2, inv2;
  row_stats(tid, l, mean2, inv2);
  load8(w2, tid, wv);
  load8(b2, tid, bv);
#pragma unroll
  for (int i = 0; i < 8; ++i) o[i] = (l[i] - mean2) * inv2 * wv[i] + bv[i];
  store8bf(x2 + (size_t)row * HH, tid, o);
}

// out = lnin + LN4(mlp+mlp2)
__global__ __launch_bounds__(256) void fuse_out_kernel(
    const bf16_t* __restrict__ mlp, const bf16_t* __restrict__ mlp2,
    const bf16_t* __restrict__ lnin,
    const float* __restrict__ w4, const float* __restrict__ b4,
    float* __restrict__ out) {
  const int row = blockIdx.x, tid = threadIdx.x;
  float m[8], m2[8], l[8], wv[8], bv[8], o[8];
  load8bf(mlp + (size_t)row * HH, tid, m);
  load8bf(mlp2 + (size_t)row * HH, tid, m2);
#pragma unroll
  for (int i = 0; i < 8; ++i) m[i] += m2[i];
  float mean4, inv4;
  row_stats(tid, m, mean4, inv4);
  load8bf(lnin + (size_t)row * HH, tid, l);
  load8(w4, tid, wv);
  load8(b4, tid, bv);
#pragma unroll
  for (int i = 0; i < 8; ++i) o[i] = l[i] + (m[i] - mean4) * inv4 * wv[i] + bv[i];
  store8f(out + (size_t)row * HH, tid, o);
}

// ================= 256x256 8-phase GEMM (r12 core + lgkmcnt(8) throttle) =================
#define MFMA16(a, b, cc) __builtin_amdgcn_mfma_f32_16x16x32_bf16(a, b, cc, 0, 0, 0)

#define STAGE(ISB, BUF, HALF, KT) do {                                              \
    const char* _s = ((ISB) ? bS : aS) + (size_t)(HALF) * h128 + (size_t)(KT) * 128; \
    char* _d = lds + ((ISB) ? 65536 : 0) + (BUF) * 32768 + (HALF) * 16384 +         \
               wave * 1024;                                                         \
    g2l16(_s, _d);                                                                  \
    g2l16(_s + h64, _d + 8192);                                                     \
  } while (0)

#define LDA(BUF, MQ)                                                                \
  _Pragma("unroll") for (int mf = 0; mf < 4; ++mf) {                                \
    const char* _p = aRd + (BUF) * 32768 + (MQ) * 8192 + mf * 2048;                 \
    aR[mf * 2]     = *(const bf16x8*)(_p + colK0);                                  \
    aR[mf * 2 + 1] = *(const bf16x8*)(_p + colK1);                                  \
  }

#define LDB(BR, BUF, NQ)                                                            \
  _Pragma("unroll") for (int nf = 0; nf < 2; ++nf) {                                \
    const char* _p = bRd + (BUF) * 32768 + (NQ) * 4096 + nf * 2048;                 \
    BR[nf * 2]     = *(const bf16x8*)(_p + colK0);                                  \
    BR[nf * 2 + 1] = *(const bf16x8*)(_p + colK1);                                  \
  }

#define MMA(MQ, NQ, BR)                                                             \
  _Pragma("unroll") for (int mf = 0; mf < 4; ++mf)                                  \
  _Pragma("unroll") for (int nf = 0; nf < 2; ++nf)                                  \
  _Pragma("unroll") for (int ks = 0; ks < 2; ++ks)                                  \
    acc[(MQ) * 4 + mf][(NQ) * 2 + nf] =                                             \
        MFMA16(aR[mf * 2 + ks], BR[nf * 2 + ks], acc[(MQ) * 4 + mf][(NQ) * 2 + nf]);

#define PH_BEGIN()                                                                  \
  __builtin_amdgcn_s_barrier();                                                     \
  __builtin_amdgcn_s_setprio(1);

#define PH_MID()                                                                    \
  __builtin_amdgcn_s_setprio(0);

#define PH_END()                                                                    \
  __builtin_amdgcn_s_barrier();

#define LGK8() asm volatile("s_waitcnt lgkmcnt(8)" ::: "memory")

template <int EPI, int SPLITK>
__global__ __launch_bounds__(512, 2) void gemm256(
    const bf16_t* __restrict__ A, const bf16_t* __restrict__ BT,
    const float* __restrict__ bias, void* __restrict__ out0, void* __restrict__ out1,
    const int M, const int N, const int Keff, const int ldK) {
  __shared__ alignas(16) char lds[131072];
  const int tid = threadIdx.x;
  const int wave = tid >> 6, lane = tid & 63;
  const int wm = wave >> 2, wn = wave & 3;   // 2M x 4N
  const int c = lane & 15, g = lane >> 4;

  const int nwg = gridDim.x;
  int bid = (blockIdx.x & 7) * (nwg >> 3) + (blockIdx.x >> 3);
  const int nm = M >> 8;
  int slice = 0;
  if (SPLITK == 2) {
    const int per = nm * (N >> 8);
    slice = bid >= per;
    bid -= slice * per;
  }
  const int mt = bid % nm, nt = bid / nm;

  const size_t ldb = (size_t)ldK * 2;
  const size_t h64 = (size_t)64 * ldb;
  const size_t h128 = 2 * h64;
  const char* aPan = (const char*)A + (size_t)(mt * 256) * ldb + (size_t)(slice * Keff) * 2;
  const char* bPan = (const char*)BT + (size_t)(nt * 256) * ldb + (size_t)(slice * Keff) * 2;

  const int srow = tid >> 3;
  const int scb = ((tid & 7) << 4) ^ ((srow & 7) << 4);
  const char* aS = aPan + (size_t)srow * ldb + scb;
  const char* bS = bPan + (size_t)srow * ldb + scb;

  const int x4 = (c & 7) << 4;
  const int colK0 = (g * 16) ^ x4;
  const int colK1 = (64 + g * 16) ^ x4;
  const char* aRd = lds + wm * 16384 + c * 128;
  const char* bRd = lds + 65536 + (wn >> 1) * 16384 + ((wn & 1) * 64 + c) * 128;

  f32x4 acc[8][4] = {};
  bf16x8 aR[8], b0R[4], b1R[4];

  const int NITER = Keff >> 7;
  const int NT2 = NITER * 2;

  STAGE(1, 0, 0, 0); STAGE(1, 0, 1, 0); STAGE(0, 0, 0, 0); STAGE(0, 0, 1, 0);
  STAGE(1, 1, 0, 1); STAGE(1, 1, 1, 1);
  asm volatile("s_waitcnt vmcnt(4)" ::: "memory");
  __builtin_amdgcn_s_barrier();
  LDA(0, 0);
  LDB(b0R, 0, 0);

  for (int it = 0; it < NITER; ++it) {
    const int ktb = 2 * it + 1;
    int kt2 = 2 * it + 2; if (kt2 >= NT2) kt2 = 0;
    int kt3 = 2 * it + 3; if (kt3 >= NT2) kt3 = 0;
    STAGE(0, 1, 0, ktb);
    PH_BEGIN(); MMA(0, 0, b0R); PH_MID();
    LDB(b1R, 0, 1);
    PH_END();
    STAGE(0, 1, 1, ktb);
    PH_BEGIN(); MMA(0, 1, b1R); PH_MID();
    LDA(0, 1);
    PH_END();
    STAGE(1, 0, 0, kt2);
    PH_BEGIN(); MMA(1, 1, b1R); PH_MID();
    PH_END();
    STAGE(1, 0, 1, kt2);
    asm volatile("s_waitcnt vmcnt(4)" ::: "memory");
    PH_BEGIN(); MMA(1, 0, b0R); PH_MID();
    LDA(1, 0); LDB(b0R, 1, 0);
    LGK8();   // drain first 4 of the 12 reads before crossing the barrier
    PH_END();
    STAGE(0, 0, 0, kt2);
    PH_BEGIN(); MMA(0, 0, b0R); PH_MID();
    LDB(b1R, 1, 1);
    PH_END();
    STAGE(0, 0, 1, kt2);
    PH_BEGIN(); MMA(0, 1, b1R); PH_MID();
    LDA(1, 1);
    PH_END();
    STAGE(1, 1, 0, kt3);
    PH_BEGIN(); MMA(1, 1, b1R); PH_MID();
    PH_END();
    STAGE(1, 1, 1, kt3);
    asm volatile("s_waitcnt vmcnt(4)" ::: "memory");
    PH_BEGIN(); MMA(1, 0, b0R); PH_MID();
    LDA(0, 0); LDB(b0R, 0, 0);
    LGK8();
    PH_END();
  }

  const int rowb = mt * 256 + wm * 128 + g * 4;
  const int colb = nt * 256 + wn * 64 + c;
  if constexpr (EPI == 0) {
    bf16_t* o = (bf16_t*)(slice ? out1 : out0);
    float bvv[4];
#pragma unroll
    for (int nf = 0; nf < 4; ++nf) bvv[nf] = (slice == 0) ? bias[colb + nf * 16] : 0.0f;
#pragma unroll
    for (int mf = 0; mf < 8; ++mf) {
      const int r = rowb + mf * 16;
#pragma unroll
      for (int e = 0; e < 4; ++e) {
        bf16_t* orow = o + (size_t)(r + e) * N + colb;
#pragma unroll
        for (int nf = 0; nf < 4; ++nf)
          orow[nf * 16] = f2bf(acc[mf][nf][e] + bvv[nf]);
      }
    }
  } else if constexpr (EPI == 1) {
    bf16_t* o = (bf16_t*)out0;
    float bvv[4];
#pragma unroll
    for (int nf = 0; nf < 4; ++nf) bvv[nf] = bias[colb + nf * 16];
#pragma unroll
    for (int mf = 0; mf < 8; ++mf) {
      const int r = rowb + mf * 16;
#pragma unroll
      for (int e = 0; e < 4; ++e) {
        bf16_t* orow = o + (size_t)(r + e) * N + colb;
#pragma unroll
        for (int nf = 0; nf < 4; ++nf)
          orow[nf * 16] = f2bf(acc[mf][nf][e] + bvv[nf]);
      }
    }
  } else {
    bf16_t* o = (bf16_t*)out0;
    float bvv[4];
#pragma unroll
    for (int nf = 0; nf < 4; ++nf) bvv[nf] = bias[colb + nf * 16];
#pragma unroll
    for (int mf = 0; mf < 8; ++mf) {
      const int r = rowb + mf * 16;
#pragma unroll
      for (int e = 0; e < 4; ++e) {
        bf16_t* orow = o + (size_t)(r + e) * N + colb;
#pragma unroll
        for (int nf = 0; nf < 4; ++nf) {
          float u = acc[mf][nf][e] + bvv[nf];
          float cc2 = 0.7978845608f * (u + 0.044715f * u * u * u);
          float ex = __expf(2.0f * cc2);
          float th = 1.0f - 2.0f / (ex + 1.0f);
          orow[nf * 16] = f2bf(0.5f * u * (1.0f + th));
        }
      }
    }
  }
}

// ---------------- flash attention: QBLK=128, KV tiles of 64, double-buffered, setprio ----------------
__global__ __launch_bounds__(512) void attn_kernel(
    const bf16_t* __restrict__ qkv, const bf16_t* __restrict__ vT,
    bf16_t* __restrict__ ctx) {
  __shared__ alignas(16) char Ksm[2][8192];
  __shared__ alignas(16) char Vsm[2][8192];
  __shared__ alignas(16) char Psm[16384];

  const int id = blockIdx.x;
  const int qt = 7 - (id >> 7);
  const int bh = id & 127;
  const int b = bh >> 5, h = bh & 31;
  const int tid = threadIdx.x;
  const int wave = tid >> 6;
  const int lane = tid & 63;
  const int q0 = qt * 128;
  const int q0w = q0 + wave * 16;
  const int c = lane & 15;
  const int g = lane >> 4;

  const bf16_t* qb = qkv + ((size_t)b * SS + q0w) * QKVLD + h * HDD;
  const bf16x8 qa0 = *(const bf16x8*)(qb + (size_t)c * QKVLD + g * 8);
  const bf16x8 qa1 = *(const bf16x8*)(qb + (size_t)c * QKVLD + 32 + g * 8);

  f32x4 o[4] = {};
  float mrow[4], lrow[4];
#pragma unroll
  for (int e = 0; e < 4; ++e) { mrow[e] = -1e30f; lrow[e] = 0.0f; }

  const int sr = tid >> 3;
  const int sgb = ((tid & 7) * 16) ^ ((sr & 7) << 4);
  const char* kgb = (const char*)(qkv + (size_t)b * SS * QKVLD + HH + h * HDD);
  const char* vgb = (const char*)(vT + (size_t)bh * HDD * SS);
  char* Pw = Psm + wave * 2048;

  const int ntiles = (q0 + 128) >> 6;

  {
    g2l16(kgb + (size_t)sr * (QKVLD * 2) + sgb, Ksm[0] + wave * 1024);
    g2l16(vgb + (size_t)sr * 2048 + sgb, Vsm[0] + wave * 1024);
  }
  __syncthreads();

  for (int t = 0; t < ntiles; ++t) {
    const int kb = t * 64;
    const int cur = t & 1;
    if (t + 1 < ntiles) {
      const int kb1 = kb + 64;
      g2l16(kgb + (size_t)(kb1 + sr) * (QKVLD * 2) + sgb, Ksm[cur ^ 1] + wave * 1024);
      g2l16(vgb + (size_t)sr * 2048 + (size_t)kb1 * 2 + sgb, Vsm[cur ^ 1] + wave * 1024);
    }

    if (kb < q0w + 16) {
      f32x4 s[4] = {};
      __builtin_amdgcn_s_setprio(1);
#pragma unroll
      for (int sub = 0; sub < 4; ++sub) {
        const int n = sub * 16 + c;
        const int x = (n & 7) << 4;
        bf16x8 kf0 = *(const bf16x8*)(Ksm[cur] + n * 128 + ((g * 16) ^ x));
        bf16x8 kf1 = *(const bf16x8*)(Ksm[cur] + n * 128 + ((64 + g * 16) ^ x));
        s[sub] = MFMA16(qa0, kf0, s[sub]);
        s[sub] = MFMA16(qa1, kf1, s[sub]);
      }
      __builtin_amdgcn_s_setprio(0);
      const bool diag = (kb + 63 > q0w);
      float pv[4][4];
#pragma unroll
      for (int sub = 0; sub < 4; ++sub)
#pragma unroll
        for (int e = 0; e < 4; ++e) {
          float sv = s[sub][e] * 0.125f;
          if (diag && (kb + sub * 16 + c > q0w + g * 4 + e)) sv = -10000.0f;
          pv[sub][e] = sv;
        }
      float scale[4];
#pragma unroll
      for (int e = 0; e < 4; ++e) {
        float mx = fmaxf(fmaxf(pv[0][e], pv[1][e]), fmaxf(pv[2][e], pv[3][e]));
        mx = fmaxf(mx, __shfl_xor(mx, 1, 64));
        mx = fmaxf(mx, __shfl_xor(mx, 2, 64));
        mx = fmaxf(mx, __shfl_xor(mx, 4, 64));
        mx = fmaxf(mx, __shfl_xor(mx, 8, 64));
        const float mnew = fmaxf(mrow[e], mx);
        scale[e] = __expf(mrow[e] - mnew);
        mrow[e] = mnew;
      }
#pragma unroll
      for (int e = 0; e < 4; ++e) {
        const int row = g * 4 + e;
        const int xr = (row & 7) << 4;
        float sum = 0.0f;
#pragma unroll
        for (int sub = 0; sub < 4; ++sub) {
          float p = __expf(pv[sub][e] - mrow[e]);
          sum += p;
          const int cb = (sub * 16 + c) * 2;
          *(bf16_t*)(Pw + row * 128 + (cb ^ xr)) = f2bf(p);
        }
        sum += __shfl_xor(sum, 1, 64);
        sum += __shfl_xor(sum, 2, 64);
        sum += __shfl_xor(sum, 4, 64);
        sum += __shfl_xor(sum, 8, 64);
        lrow[e] = lrow[e] * scale[e] + sum;
      }
#pragma unroll
      for (int d = 0; d < 4; ++d)
#pragma unroll
        for (int e = 0; e < 4; ++e) o[d][e] *= scale[e];
      const int xa = (c & 7) << 4;
      bf16x8 pa0 = *(const bf16x8*)(Pw + c * 128 + ((g * 16) ^ xa));
      bf16x8 pa1 = *(const bf16x8*)(Pw + c * 128 + ((64 + g * 16) ^ xa));
      __builtin_amdgcn_s_setprio(1);
#pragma unroll
      for (int d = 0; d < 4; ++d) {
        const int n = d * 16 + c;
        const int xv = (n & 7) << 4;
        bf16x8 vf0 = *(const bf16x8*)(Vsm[cur] + n * 128 + ((g * 16) ^ xv));
        bf16x8 vf1 = *(const bf16x8*)(Vsm[cur] + n * 128 + ((64 + g * 16) ^ xv));
        o[d] = MFMA16(pa0, vf0, o[d]);
        o[d] = MFMA16(pa1, vf1, o[d]);
      }
      __builtin_amdgcn_s_setprio(0);
    }
    __syncthreads();
  }

#pragma unroll
  for (int e = 0; e < 4; ++e) {
    const int qrow = q0w + g * 4 + e;
    const float inv = 1.0f / lrow[e];
#pragma unroll
    for (int d = 0; d < 4; ++d)
      ctx[((size_t)b * SS + qrow) * HH + h * 64 + d * 16 + c] = f2bf(o[d][e] * inv);
  }
}

// ---------------- host ----------------
extern "C" void kernel_launch(void* const* d_in, const int* in_sizes, int n_in,
                              void* d_out, int out_size, void* d_ws, size_t ws_size,
                              hipStream_t stream) {
  const float* hidden = (const float*)d_in[0];
  const float* ln1w = (const float*)d_in[2];
  const float* ln1b = (const float*)d_in[3];
  const float* wqkv = (const float*)d_in[4];
  const float* bqkv = (const float*)d_in[5];
  const float* wdense = (const float*)d_in[6];
  const float* bdense = (const float*)d_in[7];
  const float* ln3w = (const float*)d_in[8];
  const float* ln3b = (const float*)d_in[9];
  const float* ln2w = (const float*)d_in[10];
  const float* ln2b = (const float*)d_in[11];
  const float* wh4h = (const float*)d_in[12];
  const float* bh4h = (const float*)d_in[13];
  const float* w4hh = (const float*)d_in[14];
  const float* b4hh = (const float*)d_in[15];
  const float* ln4w = (const float*)d_in[16];
  const float* ln4b = (const float*)d_in[17];

  char* ws = (char*)d_ws;
  bf16_t* wqkvT = (bf16_t*)(ws + OFF_WQKV);
  bf16_t* wdenseT = (bf16_t*)(ws + OFF_WDENSE);
  bf16_t* wh4hT = (bf16_t*)(ws + OFF_WH4H);
  bf16_t* w4hhT = (bf16_t*)(ws + OFF_W4HH);
  bf16_t* x1 = (bf16_t*)(ws + OFF_X1);
  bf16_t* qkv = (bf16_t*)(ws + OFF_QKV);
  bf16_t* vT = (bf16_t*)(ws + OFF_VT);
  bf16_t* ctx = (bf16_t*)(ws + OFF_X1);
  bf16_t* attnd = (bf16_t*)(ws + OFF_QKV);
  bf16_t* attnd2 = (bf16_t*)(ws + OFF_ATTND2);
  bf16_t* lnin = (bf16_t*)(ws + OFF_LNIN);
  bf16_t* x2 = (bf16_t*)(ws + OFF_X1);
  bf16_t* inter = (bf16_t*)(ws + OFF_QKV);
  bf16_t* mlp = (bf16_t*)(ws + OFF_MLP);
  bf16_t* mlp2 = (bf16_t*)(ws + OFF_MLP2);

  convert_ln1_kernel<<<dim3(49152 + MTOK), 256, 0, stream>>>(
      wqkv, wqkvT, wdense, wdenseT, wh4h, wh4hT, w4hh, w4hhT,
      hidden, ln1w, ln1b, x1);

  gemm256<1, 1><<<dim3((6144 / 256) * (4096 / 256)), 512, 0, stream>>>(
      x1, wqkvT, bqkv, (void*)qkv, nullptr, MTOK, 6144, 2048, 2048);

  dim3 tb(32, 8);
  transpose_v_kernel<<<dim3(SS / 32, HDD / 32, BB * NHH), tb, 0, stream>>>(qkv, vT);

  attn_kernel<<<dim3(1024), 512, 0, stream>>>(qkv, vT, ctx);

  gemm256<0, 2><<<dim3((2048 / 256) * (4096 / 256) * 2), 512, 0, stream>>>(
      ctx, wdenseT, bdense, (void*)attnd, (void*)attnd2, MTOK, 2048, 1024, 2048);

  fuse_mid_kernel<<<MTOK, 256, 0, stream>>>(attnd, attnd2, hidden, ln3w, ln3b, ln2w, ln2b, lnin, x2);

  gemm256<2, 1><<<dim3((8192 / 256) * (4096 / 256)), 512, 0, stream>>>(
      x2, wh4hT, bh4h, (void*)inter, nullptr, MTOK, 8192, 2048, 2048);

  gemm256<0, 2><<<dim3((2048 / 256) * (4096 / 256) * 2), 512, 0, stream>>>(
      inter, w4hhT, b4hh, (void*)mlp, (void*)mlp2, MTOK, 2048, 4096, 8192);

  fuse_out_kernel<<<MTOK, 256, 0, stream>>>(mlp, mlp2, lnin, ln4w, ln4b, (float*)d_out);
}

// Round 15
// 575.160 us; speedup vs baseline: 1.0124x; 1.0124x over previous
//
#include <hip/hip_runtime.h>
#include <cstdint>
#include <cstddef>

typedef __bf16 bf16_t;
typedef __bf16 bf16x8 __attribute__((ext_vector_type(8)));
typedef float f32x4 __attribute__((ext_vector_type(4)));

// Problem dims
#define BB 4
#define SS 1024
#define HH 2048
#define NHH 32
#define HDD 64
#define MTOK 4096   // B*S
#define QKVLD 6144  // fused qkv row stride (elements)

// -------- workspace layout (bytes), total 251,658,240 (240 MiB) --------
static constexpr size_t OFF_WQKV   = 0;
static constexpr size_t OFF_WDENSE = 25165824;
static constexpr size_t OFF_WH4H   = 33554432;
static constexpr size_t OFF_W4HH   = 67108864;
static constexpr size_t OFF_X1     = 100663296;
static constexpr size_t OFF_QKV    = 117440512;
static constexpr size_t OFF_ATTND2 = 150994944;
static constexpr size_t OFF_VT     = 167772160;
static constexpr size_t OFF_LNIN   = 184549376;   // bf16 8 MB
static constexpr size_t OFF_MLP    = 218103808;
static constexpr size_t OFF_MLP2   = 234881024;

__device__ __forceinline__ uint16_t f2bfu(float f) {
  union { float f; uint32_t u; } v; v.f = f;
  return (uint16_t)((v.u + 0x7FFFu + ((v.u >> 16) & 1u)) >> 16);
}
__device__ __forceinline__ bf16_t f2bf(float f) {
  union { uint16_t u; bf16_t b; } o; o.u = f2bfu(f);
  return o.b;
}
__device__ __forceinline__ float bfu2f(uint16_t u) {
  union { uint32_t u; float f; } v; v.u = ((uint32_t)u) << 16;
  return v.f;
}

__device__ __forceinline__ void g2l16(const void* g, void* l) {
  __builtin_amdgcn_global_load_lds(
      (const __attribute__((address_space(1))) void*)g,
      (__attribute__((address_space(3))) void*)l, 16, 0, 0);
}

// ---------------- row helpers (rows of 2048, 256 flat threads, 8 elems/thread) ----------------
__device__ __forceinline__ void block_reduce2(int tid, float& s, float& ss) {
#pragma unroll
  for (int o = 32; o > 0; o >>= 1) {
    s += __shfl_down(s, o, 64);
    ss += __shfl_down(ss, o, 64);
  }
  __shared__ float red[8];
  const int wave = tid >> 6;
  const int lane = tid & 63;
  if (lane == 0) { red[wave] = s; red[4 + wave] = ss; }
  __syncthreads();
  s = red[0] + red[1] + red[2] + red[3];
  ss = red[4] + red[5] + red[6] + red[7];
  __syncthreads();
}

__device__ __forceinline__ void load8(const float* base, int tid, float* v) {
  float4 a = ((const float4*)base)[tid];
  float4 b = ((const float4*)base)[tid + 256];
  v[0] = a.x; v[1] = a.y; v[2] = a.z; v[3] = a.w;
  v[4] = b.x; v[5] = b.y; v[6] = b.z; v[7] = b.w;
}
__device__ __forceinline__ void load8bf(const bf16_t* base, int tid, float* v) {
  ushort4 a = ((const ushort4*)base)[tid];
  ushort4 b = ((const ushort4*)base)[tid + 256];
  v[0] = bfu2f(a.x); v[1] = bfu2f(a.y); v[2] = bfu2f(a.z); v[3] = bfu2f(a.w);
  v[4] = bfu2f(b.x); v[5] = bfu2f(b.y); v[6] = bfu2f(b.z); v[7] = bfu2f(b.w);
}
__device__ __forceinline__ void store8f(float* base, int tid, const float* v) {
  ((float4*)base)[tid] = make_float4(v[0], v[1], v[2], v[3]);
  ((float4*)base)[tid + 256] = make_float4(v[4], v[5], v[6], v[7]);
}
__device__ __forceinline__ void store8bf(bf16_t* base, int tid, const float* v) {
  ushort4 o0 = {f2bfu(v[0]), f2bfu(v[1]), f2bfu(v[2]), f2bfu(v[3])};
  ushort4 o1 = {f2bfu(v[4]), f2bfu(v[5]), f2bfu(v[6]), f2bfu(v[7])};
  ((ushort4*)base)[tid] = o0;
  ((ushort4*)base)[tid + 256] = o1;
}
__device__ __forceinline__ void row_stats(int tid, const float* v, float& mean, float& inv) {
  float s = 0.f, ss = 0.f;
#pragma unroll
  for (int i = 0; i < 8; ++i) { s += v[i]; ss += v[i] * v[i]; }
  block_reduce2(tid, s, ss);
  mean = s * (1.0f / 2048.0f);
  float var = ss * (1.0f / 2048.0f) - mean * mean;
  inv = rsqrtf(var + 1e-5f);
}

// ---------------- merged: weight convert+transpose (4 weights) + LN1, 1 launch ----------------
__global__ void convert_ln1_kernel(const float* __restrict__ w0, bf16_t* __restrict__ o0,
                                   const float* __restrict__ w1, bf16_t* __restrict__ o1,
                                   const float* __restrict__ w2, bf16_t* __restrict__ o2,
                                   const float* __restrict__ w3, bf16_t* __restrict__ o3,
                                   const float* __restrict__ hid,
                                   const float* __restrict__ ln1w, const float* __restrict__ ln1b,
                                   bf16_t* __restrict__ x1) {
  const int id = blockIdx.x;
  const int tx = threadIdx.x & 31, ty = threadIdx.x >> 5;
  if (id >= 49152) {   // LN1 rows
    const int row = id - 49152, tid = threadIdx.x;
    float v[8], wv[8], bv[8], o[8];
    load8(hid + (size_t)row * HH, tid, v);
    float mean, inv;
    row_stats(tid, v, mean, inv);
    load8(ln1w, tid, wv);
    load8(ln1b, tid, bv);
#pragma unroll
    for (int i = 0; i < 8; ++i) o[i] = (v[i] - mean) * inv * wv[i] + bv[i];
    store8bf(x1 + (size_t)row * HH, tid, o);
    return;
  }
  __shared__ float t[32][33];
  const float* W; bf16_t* WT; int K, N, nt, idx;
  if (id < 12288)      { W = w0; WT = o0; K = 2048; N = 6144; nt = 192; idx = id; }
  else if (id < 16384) { W = w1; WT = o1; K = 2048; N = 2048; nt = 64;  idx = id - 12288; }
  else if (id < 32768) { W = w2; WT = o2; K = 2048; N = 8192; nt = 256; idx = id - 16384; }
  else                 { W = w3; WT = o3; K = 8192; N = 2048; nt = 64;  idx = id - 32768; }
  const int n0 = (idx % nt) * 32;
  const int k0 = (idx / nt) * 32;
#pragma unroll
  for (int j = 0; j < 4; ++j)
    t[ty + j * 8][tx] = W[(size_t)(k0 + ty + j * 8) * N + n0 + tx];
  __syncthreads();
#pragma unroll
  for (int j = 0; j < 4; ++j)
    WT[(size_t)(n0 + ty + j * 8) * K + k0 + tx] = f2bf(t[tx][ty + j * 8]);
}

// ---------------- v (strided in fused qkv) -> vT [B,NH,HD,S] (bf16) ----------------
__global__ void transpose_v_kernel(const bf16_t* __restrict__ qkv, bf16_t* __restrict__ vT) {
  __shared__ bf16_t t[32][33];
  const int s0 = blockIdx.x * 32;
  const int d0 = blockIdx.y * 32;
  const int bh = blockIdx.z;
  const int b = bh >> 5, h = bh & 31;
  const int tx = threadIdx.x, ty = threadIdx.y;
  const bf16_t* src = qkv + (size_t)b * SS * QKVLD + 2 * HH + h * HDD;
#pragma unroll
  for (int j = 0; j < 4; ++j)
    t[ty + j * 8][tx] = src[(size_t)(s0 + ty + j * 8) * QKVLD + d0 + tx];
  __syncthreads();
  bf16_t* dst = vT + (size_t)bh * HDD * SS;
#pragma unroll
  for (int j = 0; j < 4; ++j)
    dst[(size_t)(d0 + ty + j * 8) * SS + s0 + tx] = t[tx][ty + j * 8];
}

// LN3(ad+ad2) ; lnin = hidden + ln3 (bf16) ; x2 = LN2(lnin) bf16
__global__ __launch_bounds__(256) void fuse_mid_kernel(
    const bf16_t* __restrict__ ad, const bf16_t* __restrict__ ad2,
    const float* __restrict__ hid,
    const float* __restrict__ w3, const float* __restrict__ b3,
    const float* __restrict__ w2, const float* __restrict__ b2,
    bf16_t* __restrict__ lnin, bf16_t* __restrict__ x2) {
  const int row = blockIdx.x, tid = threadIdx.x;
  float a[8], a2[8], h[8], wv[8], bv[8], l[8], o[8];
  load8bf(ad + (size_t)row * HH, tid, a);
  load8bf(ad2 + (size_t)row * HH, tid, a2);
#pragma unroll
  for (int i = 0; i < 8; ++i) a[i] += a2[i];
  float mean3, inv3;
  row_stats(tid, a, mean3, inv3);
  load8(hid + (size_t)row * HH, tid, h);
  load8(w3, tid, wv);
  load8(b3, tid, bv);
#pragma unroll
  for (int i = 0; i < 8; ++i) l[i] = h[i] + (a[i] - mean3) * inv3 * wv[i] + bv[i];
  store8bf(lnin + (size_t)row * HH, tid, l);
  float mean2, inv2;
  row_stats(tid, l, mean2, inv2);
  load8(w2, tid, wv);
  load8(b2, tid, bv);
#pragma unroll
  for (int i = 0; i < 8; ++i) o[i] = (l[i] - mean2) * inv2 * wv[i] + bv[i];
  store8bf(x2 + (size_t)row * HH, tid, o);
}

// out = lnin + LN4(mlp+mlp2)
__global__ __launch_bounds__(256) void fuse_out_kernel(
    const bf16_t* __restrict__ mlp, const bf16_t* __restrict__ mlp2,
    const bf16_t* __restrict__ lnin,
    const float* __restrict__ w4, const float* __restrict__ b4,
    float* __restrict__ out) {
  const int row = blockIdx.x, tid = threadIdx.x;
  float m[8], m2[8], l[8], wv[8], bv[8], o[8];
  load8bf(mlp + (size_t)row * HH, tid, m);
  load8bf(mlp2 + (size_t)row * HH, tid, m2);
#pragma unroll
  for (int i = 0; i < 8; ++i) m[i] += m2[i];
  float mean4, inv4;
  row_stats(tid, m, mean4, inv4);
  load8bf(lnin + (size_t)row * HH, tid, l);
  load8(w4, tid, wv);
  load8(b4, tid, bv);
#pragma unroll
  for (int i = 0; i < 8; ++i) o[i] = l[i] + (m[i] - mean4) * inv4 * wv[i] + bv[i];
  store8f(out + (size_t)row * HH, tid, o);
}

// ================= 256x256 8-phase GEMM (r12 core; SUPERTILED grid mapping) =================
// Mapping: bid -> supertile band of GM=4 mt rows, nt-fastest within the band, so each
// XCD's contiguous bid chunk covers 4 mt x many nt: its 4 MB A-band stays L2-resident
// (staging loads hit L2 ~200cyc instead of HBM ~900cyc -> vmcnt(4) drains covered).
#define MFMA16(a, b, cc) __builtin_amdgcn_mfma_f32_16x16x32_bf16(a, b, cc, 0, 0, 0)

#define STAGE(ISB, BUF, HALF, KT) do {                                              \
    const char* _s = ((ISB) ? bS : aS) + (size_t)(HALF) * h128 + (size_t)(KT) * 128; \
    char* _d = lds + ((ISB) ? 65536 : 0) + (BUF) * 32768 + (HALF) * 16384 +         \
               wave * 1024;                                                         \
    g2l16(_s, _d);                                                                  \
    g2l16(_s + h64, _d + 8192);                                                     \
  } while (0)

#define LDA(BUF, MQ)                                                                \
  _Pragma("unroll") for (int mf = 0; mf < 4; ++mf) {                                \
    const char* _p = aRd + (BUF) * 32768 + (MQ) * 8192 + mf * 2048;                 \
    aR[mf * 2]     = *(const bf16x8*)(_p + colK0);                                  \
    aR[mf * 2 + 1] = *(const bf16x8*)(_p + colK1);                                  \
  }

#define LDB(BR, BUF, NQ)                                                            \
  _Pragma("unroll") for (int nf = 0; nf < 2; ++nf) {                                \
    const char* _p = bRd + (BUF) * 32768 + (NQ) * 4096 + nf * 2048;                 \
    BR[nf * 2]     = *(const bf16x8*)(_p + colK0);                                  \
    BR[nf * 2 + 1] = *(const bf16x8*)(_p + colK1);                                  \
  }

#define MMA(MQ, NQ, BR)                                                             \
  _Pragma("unroll") for (int mf = 0; mf < 4; ++mf)                                  \
  _Pragma("unroll") for (int nf = 0; nf < 2; ++nf)                                  \
  _Pragma("unroll") for (int ks = 0; ks < 2; ++ks)                                  \
    acc[(MQ) * 4 + mf][(NQ) * 2 + nf] =                                             \
        MFMA16(aR[mf * 2 + ks], BR[nf * 2 + ks], acc[(MQ) * 4 + mf][(NQ) * 2 + nf]);

#define PH_BEGIN()                                                                  \
  __builtin_amdgcn_s_barrier();                                                     \
  __builtin_amdgcn_s_setprio(1);

#define PH_MID()                                                                    \
  __builtin_amdgcn_s_setprio(0);

#define PH_END()                                                                    \
  __builtin_amdgcn_s_barrier();

#define LGK8() asm volatile("s_waitcnt lgkmcnt(8)" ::: "memory")

template <int EPI, int SPLITK>
__global__ __launch_bounds__(512, 2) void gemm256(
    const bf16_t* __restrict__ A, const bf16_t* __restrict__ BT,
    const float* __restrict__ bias, void* __restrict__ out0, void* __restrict__ out1,
    const int M, const int N, const int Keff, const int ldK) {
  __shared__ alignas(16) char lds[131072];
  const int tid = threadIdx.x;
  const int wave = tid >> 6, lane = tid & 63;
  const int wm = wave >> 2, wn = wave & 3;   // 2M x 4N
  const int c = lane & 15, g = lane >> 4;

  // bijective XCD swizzle, then supertile (GM=4 mt-band, nt-fastest)
  const int nwg = gridDim.x;
  int bid = (blockIdx.x & 7) * (nwg >> 3) + (blockIdx.x >> 3);
  const int nm = M >> 8;
  const int nn = N >> 8;
  int slice = 0;
  if (SPLITK == 2) {
    const int per = nm * nn;
    slice = bid >= per;
    bid -= slice * per;
  }
  const int band = bid / (4 * nn);
  const int rem = bid - band * (4 * nn);
  const int mt = band * 4 + (rem & 3);
  const int nt = rem >> 2;

  const size_t ldb = (size_t)ldK * 2;
  const size_t h64 = (size_t)64 * ldb;
  const size_t h128 = 2 * h64;
  const char* aPan = (const char*)A + (size_t)(mt * 256) * ldb + (size_t)(slice * Keff) * 2;
  const char* bPan = (const char*)BT + (size_t)(nt * 256) * ldb + (size_t)(slice * Keff) * 2;

  const int srow = tid >> 3;
  const int scb = ((tid & 7) << 4) ^ ((srow & 7) << 4);
  const char* aS = aPan + (size_t)srow * ldb + scb;
  const char* bS = bPan + (size_t)srow * ldb + scb;

  const int x4 = (c & 7) << 4;
  const int colK0 = (g * 16) ^ x4;
  const int colK1 = (64 + g * 16) ^ x4;
  const char* aRd = lds + wm * 16384 + c * 128;
  const char* bRd = lds + 65536 + (wn >> 1) * 16384 + ((wn & 1) * 64 + c) * 128;

  f32x4 acc[8][4] = {};
  bf16x8 aR[8], b0R[4], b1R[4];

  const int NITER = Keff >> 7;
  const int NT2 = NITER * 2;

  STAGE(1, 0, 0, 0); STAGE(1, 0, 1, 0); STAGE(0, 0, 0, 0); STAGE(0, 0, 1, 0);
  STAGE(1, 1, 0, 1); STAGE(1, 1, 1, 1);
  asm volatile("s_waitcnt vmcnt(4)" ::: "memory");
  __builtin_amdgcn_s_barrier();
  LDA(0, 0);
  LDB(b0R, 0, 0);

  for (int it = 0; it < NITER; ++it) {
    const int ktb = 2 * it + 1;
    int kt2 = 2 * it + 2; if (kt2 >= NT2) kt2 = 0;
    int kt3 = 2 * it + 3; if (kt3 >= NT2) kt3 = 0;
    STAGE(0, 1, 0, ktb);
    PH_BEGIN(); MMA(0, 0, b0R); PH_MID();
    LDB(b1R, 0, 1);
    PH_END();
    STAGE(0, 1, 1, ktb);
    PH_BEGIN(); MMA(0, 1, b1R); PH_MID();
    LDA(0, 1);
    PH_END();
    STAGE(1, 0, 0, kt2);
    PH_BEGIN(); MMA(1, 1, b1R); PH_MID();
    PH_END();
    STAGE(1, 0, 1, kt2);
    asm volatile("s_waitcnt vmcnt(4)" ::: "memory");
    PH_BEGIN(); MMA(1, 0, b0R); PH_MID();
    LDA(1, 0); LDB(b0R, 1, 0);
    LGK8();
    PH_END();
    STAGE(0, 0, 0, kt2);
    PH_BEGIN(); MMA(0, 0, b0R); PH_MID();
    LDB(b1R, 1, 1);
    PH_END();
    STAGE(0, 0, 1, kt2);
    PH_BEGIN(); MMA(0, 1, b1R); PH_MID();
    LDA(1, 1);
    PH_END();
    STAGE(1, 1, 0, kt3);
    PH_BEGIN(); MMA(1, 1, b1R); PH_MID();
    PH_END();
    STAGE(1, 1, 1, kt3);
    asm volatile("s_waitcnt vmcnt(4)" ::: "memory");
    PH_BEGIN(); MMA(1, 0, b0R); PH_MID();
    LDA(0, 0); LDB(b0R, 0, 0);
    LGK8();
    PH_END();
  }

  const int rowb = mt * 256 + wm * 128 + g * 4;
  const int colb = nt * 256 + wn * 64 + c;
  if constexpr (EPI == 0) {
    bf16_t* o = (bf16_t*)(slice ? out1 : out0);
    float bvv[4];
#pragma unroll
    for (int nf = 0; nf < 4; ++nf) bvv[nf] = (slice == 0) ? bias[colb + nf * 16] : 0.0f;
#pragma unroll
    for (int mf = 0; mf < 8; ++mf) {
      const int r = rowb + mf * 16;
#pragma unroll
      for (int e = 0; e < 4; ++e) {
        bf16_t* orow = o + (size_t)(r + e) * N + colb;
#pragma unroll
        for (int nf = 0; nf < 4; ++nf)
          orow[nf * 16] = f2bf(acc[mf][nf][e] + bvv[nf]);
      }
    }
  } else if constexpr (EPI == 1) {
    bf16_t* o = (bf16_t*)out0;
    float bvv[4];
#pragma unroll
    for (int nf = 0; nf < 4; ++nf) bvv[nf] = bias[colb + nf * 16];
#pragma unroll
    for (int mf = 0; mf < 8; ++mf) {
      const int r = rowb + mf * 16;
#pragma unroll
      for (int e = 0; e < 4; ++e) {
        bf16_t* orow = o + (size_t)(r + e) * N + colb;
#pragma unroll
        for (int nf = 0; nf < 4; ++nf)
          orow[nf * 16] = f2bf(acc[mf][nf][e] + bvv[nf]);
      }
    }
  } else {
    bf16_t* o = (bf16_t*)out0;
    float bvv[4];
#pragma unroll
    for (int nf = 0; nf < 4; ++nf) bvv[nf] = bias[colb + nf * 16];
#pragma unroll
    for (int mf = 0; mf < 8; ++mf) {
      const int r = rowb + mf * 16;
#pragma unroll
      for (int e = 0; e < 4; ++e) {
        bf16_t* orow = o + (size_t)(r + e) * N + colb;
#pragma unroll
        for (int nf = 0; nf < 4; ++nf) {
          float u = acc[mf][nf][e] + bvv[nf];
          float cc2 = 0.7978845608f * (u + 0.044715f * u * u * u);
          float ex = __expf(2.0f * cc2);
          float th = 1.0f - 2.0f / (ex + 1.0f);
          orow[nf * 16] = f2bf(0.5f * u * (1.0f + th));
        }
      }
    }
  }
}

// ---------------- flash attention: QBLK=128, KV tiles of 64, double-buffered, setprio ----------------
__global__ __launch_bounds__(512) void attn_kernel(
    const bf16_t* __restrict__ qkv, const bf16_t* __restrict__ vT,
    bf16_t* __restrict__ ctx) {
  __shared__ alignas(16) char Ksm[2][8192];
  __shared__ alignas(16) char Vsm[2][8192];
  __shared__ alignas(16) char Psm[16384];

  const int id = blockIdx.x;
  const int qt = 7 - (id >> 7);
  const int bh = id & 127;
  const int b = bh >> 5, h = bh & 31;
  const int tid = threadIdx.x;
  const int wave = tid >> 6;
  const int lane = tid & 63;
  const int q0 = qt * 128;
  const int q0w = q0 + wave * 16;
  const int c = lane & 15;
  const int g = lane >> 4;

  const bf16_t* qb = qkv + ((size_t)b * SS + q0w) * QKVLD + h * HDD;
  const bf16x8 qa0 = *(const bf16x8*)(qb + (size_t)c * QKVLD + g * 8);
  const bf16x8 qa1 = *(const bf16x8*)(qb + (size_t)c * QKVLD + 32 + g * 8);

  f32x4 o[4] = {};
  float mrow[4], lrow[4];
#pragma unroll
  for (int e = 0; e < 4; ++e) { mrow[e] = -1e30f; lrow[e] = 0.0f; }

  const int sr = tid >> 3;
  const int sgb = ((tid & 7) * 16) ^ ((sr & 7) << 4);
  const char* kgb = (const char*)(qkv + (size_t)b * SS * QKVLD + HH + h * HDD);
  const char* vgb = (const char*)(vT + (size_t)bh * HDD * SS);
  char* Pw = Psm + wave * 2048;

  const int ntiles = (q0 + 128) >> 6;

  {
    g2l16(kgb + (size_t)sr * (QKVLD * 2) + sgb, Ksm[0] + wave * 1024);
    g2l16(vgb + (size_t)sr * 2048 + sgb, Vsm[0] + wave * 1024);
  }
  __syncthreads();

  for (int t = 0; t < ntiles; ++t) {
    const int kb = t * 64;
    const int cur = t & 1;
    if (t + 1 < ntiles) {
      const int kb1 = kb + 64;
      g2l16(kgb + (size_t)(kb1 + sr) * (QKVLD * 2) + sgb, Ksm[cur ^ 1] + wave * 1024);
      g2l16(vgb + (size_t)sr * 2048 + (size_t)kb1 * 2 + sgb, Vsm[cur ^ 1] + wave * 1024);
    }

    if (kb < q0w + 16) {
      f32x4 s[4] = {};
      __builtin_amdgcn_s_setprio(1);
#pragma unroll
      for (int sub = 0; sub < 4; ++sub) {
        const int n = sub * 16 + c;
        const int x = (n & 7) << 4;
        bf16x8 kf0 = *(const bf16x8*)(Ksm[cur] + n * 128 + ((g * 16) ^ x));
        bf16x8 kf1 = *(const bf16x8*)(Ksm[cur] + n * 128 + ((64 + g * 16) ^ x));
        s[sub] = MFMA16(qa0, kf0, s[sub]);
        s[sub] = MFMA16(qa1, kf1, s[sub]);
      }
      __builtin_amdgcn_s_setprio(0);
      const bool diag = (kb + 63 > q0w);
      float pv[4][4];
#pragma unroll
      for (int sub = 0; sub < 4; ++sub)
#pragma unroll
        for (int e = 0; e < 4; ++e) {
          float sv = s[sub][e] * 0.125f;
          if (diag && (kb + sub * 16 + c > q0w + g * 4 + e)) sv = -10000.0f;
          pv[sub][e] = sv;
        }
      float scale[4];
#pragma unroll
      for (int e = 0; e < 4; ++e) {
        float mx = fmaxf(fmaxf(pv[0][e], pv[1][e]), fmaxf(pv[2][e], pv[3][e]));
        mx = fmaxf(mx, __shfl_xor(mx, 1, 64));
        mx = fmaxf(mx, __shfl_xor(mx, 2, 64));
        mx = fmaxf(mx, __shfl_xor(mx, 4, 64));
        mx = fmaxf(mx, __shfl_xor(mx, 8, 64));
        const float mnew = fmaxf(mrow[e], mx);
        scale[e] = __expf(mrow[e] - mnew);
        mrow[e] = mnew;
      }
#pragma unroll
      for (int e = 0; e < 4; ++e) {
        const int row = g * 4 + e;
        const int xr = (row & 7) << 4;
        float sum = 0.0f;
#pragma unroll
        for (int sub = 0; sub < 4; ++sub) {
          float p = __expf(pv[sub][e] - mrow[e]);
          sum += p;
          const int cb = (sub * 16 + c) * 2;
          *(bf16_t*)(Pw + row * 128 + (cb ^ xr)) = f2bf(p);
        }
        sum += __shfl_xor(sum, 1, 64);
        sum += __shfl_xor(sum, 2, 64);
        sum += __shfl_xor(sum, 4, 64);
        sum += __shfl_xor(sum, 8, 64);
        lrow[e] = lrow[e] * scale[e] + sum;
      }
#pragma unroll
      for (int d = 0; d < 4; ++d)
#pragma unroll
        for (int e = 0; e < 4; ++e) o[d][e] *= scale[e];
      const int xa = (c & 7) << 4;
      bf16x8 pa0 = *(const bf16x8*)(Pw + c * 128 + ((g * 16) ^ xa));
      bf16x8 pa1 = *(const bf16x8*)(Pw + c * 128 + ((64 + g * 16) ^ xa));
      __builtin_amdgcn_s_setprio(1);
#pragma unroll
      for (int d = 0; d < 4; ++d) {
        const int n = d * 16 + c;
        const int xv = (n & 7) << 4;
        bf16x8 vf0 = *(const bf16x8*)(Vsm[cur] + n * 128 + ((g * 16) ^ xv));
        bf16x8 vf1 = *(const bf16x8*)(Vsm[cur] + n * 128 + ((64 + g * 16) ^ xv));
        o[d] = MFMA16(pa0, vf0, o[d]);
        o[d] = MFMA16(pa1, vf1, o[d]);
      }
      __builtin_amdgcn_s_setprio(0);
    }
    __syncthreads();
  }

#pragma unroll
  for (int e = 0; e < 4; ++e) {
    const int qrow = q0w + g * 4 + e;
    const float inv = 1.0f / lrow[e];
#pragma unroll
    for (int d = 0; d < 4; ++d)
      ctx[((size_t)b * SS + qrow) * HH + h * 64 + d * 16 + c] = f2bf(o[d][e] * inv);
  }
}

// ---------------- host ----------------
extern "C" void kernel_launch(void* const* d_in, const int* in_sizes, int n_in,
                              void* d_out, int out_size, void* d_ws, size_t ws_size,
                              hipStream_t stream) {
  const float* hidden = (const float*)d_in[0];
  const float* ln1w = (const float*)d_in[2];
  const float* ln1b = (const float*)d_in[3];
  const float* wqkv = (const float*)d_in[4];
  const float* bqkv = (const float*)d_in[5];
  const float* wdense = (const float*)d_in[6];
  const float* bdense = (const float*)d_in[7];
  const float* ln3w = (const float*)d_in[8];
  const float* ln3b = (const float*)d_in[9];
  const float* ln2w = (const float*)d_in[10];
  const float* ln2b = (const float*)d_in[11];
  const float* wh4h = (const float*)d_in[12];
  const float* bh4h = (const float*)d_in[13];
  const float* w4hh = (const float*)d_in[14];
  const float* b4hh = (const float*)d_in[15];
  const float* ln4w = (const float*)d_in[16];
  const float* ln4b = (const float*)d_in[17];

  char* ws = (char*)d_ws;
  bf16_t* wqkvT = (bf16_t*)(ws + OFF_WQKV);
  bf16_t* wdenseT = (bf16_t*)(ws + OFF_WDENSE);
  bf16_t* wh4hT = (bf16_t*)(ws + OFF_WH4H);
  bf16_t* w4hhT = (bf16_t*)(ws + OFF_W4HH);
  bf16_t* x1 = (bf16_t*)(ws + OFF_X1);
  bf16_t* qkv = (bf16_t*)(ws + OFF_QKV);
  bf16_t* vT = (bf16_t*)(ws + OFF_VT);
  bf16_t* ctx = (bf16_t*)(ws + OFF_X1);
  bf16_t* attnd = (bf16_t*)(ws + OFF_QKV);
  bf16_t* attnd2 = (bf16_t*)(ws + OFF_ATTND2);
  bf16_t* lnin = (bf16_t*)(ws + OFF_LNIN);
  bf16_t* x2 = (bf16_t*)(ws + OFF_X1);
  bf16_t* inter = (bf16_t*)(ws + OFF_QKV);
  bf16_t* mlp = (bf16_t*)(ws + OFF_MLP);
  bf16_t* mlp2 = (bf16_t*)(ws + OFF_MLP2);

  convert_ln1_kernel<<<dim3(49152 + MTOK), 256, 0, stream>>>(
      wqkv, wqkvT, wdense, wdenseT, wh4h, wh4hT, w4hh, w4hhT,
      hidden, ln1w, ln1b, x1);

  gemm256<1, 1><<<dim3((6144 / 256) * (4096 / 256)), 512, 0, stream>>>(
      x1, wqkvT, bqkv, (void*)qkv, nullptr, MTOK, 6144, 2048, 2048);

  dim3 tb(32, 8);
  transpose_v_kernel<<<dim3(SS / 32, HDD / 32, BB * NHH), tb, 0, stream>>>(qkv, vT);

  attn_kernel<<<dim3(1024), 512, 0, stream>>>(qkv, vT, ctx);

  gemm256<0, 2><<<dim3((2048 / 256) * (4096 / 256) * 2), 512, 0, stream>>>(
      ctx, wdenseT, bdense, (void*)attnd, (void*)attnd2, MTOK, 2048, 1024, 2048);

  fuse_mid_kernel<<<MTOK, 256, 0, stream>>>(attnd, attnd2, hidden, ln3w, ln3b, ln2w, ln2b, lnin, x2);

  gemm256<2, 1><<<dim3((8192 / 256) * (4096 / 256)), 512, 0, stream>>>(
      x2, wh4hT, bh4h, (void*)inter, nullptr, MTOK, 8192, 2048, 2048);

  gemm256<0, 2><<<dim3((2048 / 256) * (4096 / 256) * 2), 512, 0, stream>>>(
      inter, w4hhT, b4hh, (void*)mlp, (void*)mlp2, MTOK, 2048, 4096, 8192);

  fuse_out_kernel<<<MTOK, 256, 0, stream>>>(mlp, mlp2, lnin, ln4w, ln4b, (float*)d_out);
}